// Round 3
// baseline (849.790 us; speedup 1.0000x reference)
//
#include <hip/hip_runtime.h>

#define N_NODES 10000
#define N_EDGES 160000
#define IN_CH 128
#define H 64
#define H2 128
#define OUT_CH 112
#define NLAYERS 28

// ---------------- CSR build ----------------
__global__ __launch_bounds__(256) void k_count(const int* __restrict__ ei, int* __restrict__ deg) {
  int e = blockIdx.x * 256 + threadIdx.x;
  atomicAdd(&deg[ei[N_EDGES + e]], 1);   // E = 625*256 exactly
}

__global__ __launch_bounds__(1024) void k_scan(const int* __restrict__ deg, int* __restrict__ offs) {
  __shared__ int sums[1024];
  constexpr int CH = 10;
  int t = threadIdx.x;
  int base = t * CH;
  int local[CH];
  int s = 0;
  #pragma unroll
  for (int i = 0; i < CH; i++) {
    int idx = base + i;
    int v = (idx < N_NODES) ? deg[idx] : 0;
    local[i] = s; s += v;
  }
  sums[t] = s;
  __syncthreads();
  for (int off = 1; off < 1024; off <<= 1) {
    int v = (t >= off) ? sums[t - off] : 0;
    __syncthreads();
    sums[t] += v;
    __syncthreads();
  }
  int prev = (t == 0) ? 0 : sums[t - 1];
  #pragma unroll
  for (int i = 0; i < CH; i++) {
    int idx = base + i;
    if (idx < N_NODES) offs[idx] = prev + local[i];
  }
  if (t == 1023) offs[N_NODES] = sums[1023];
}

__global__ __launch_bounds__(256) void k_fill(const int* __restrict__ ei, const int* __restrict__ offs,
                                              int* __restrict__ cur, int* __restrict__ csr) {
  int e = blockIdx.x * 256 + threadIdx.x;
  int d = ei[N_EDGES + e];
  int p = offs[d] + atomicAdd(&cur[d], 1);
  csr[p] = ei[e];
}

// ---------------- weight packing (combined, LDS-swizzled) ----------------
// WP[l] = 16384 floats: [0,8192) = W1 packed, [8192,16384) = W2 packed.
// W1: chunk (g<16, lane<64, h<2) of 4 floats, stored with column rotation
//     col = (2*(lane&3) + h + (lane>>2)) & 7 within each 8-chunk group ->
//     every ds_read_b128 quarter-wave is exactly 2-way per bank (free).
//     chunk elements e<4: j = h*2 + (e>>1), c = e&1 -> W1[(4g+j)*128 + lane*2 + c]
// W2: chunk (g<32, lane<64): elements j<4 -> W2[(4g+j)*64 + lane]  (2-way already)
__device__ __forceinline__ int w1_off(int g, int lane, int h) {
  int col = (2 * (lane & 3) + h + (lane >> 2)) & 7;
  return (g * 128 + (lane >> 2) * 8 + col) * 4;
}

__global__ __launch_bounds__(256) void k_pack(const float* __restrict__ W1, const float* __restrict__ W2,
                                              float* __restrict__ WP) {
  int l = blockIdx.x;
  const float* w1 = W1 + l * 8192;
  const float* w2 = W2 + l * 8192;
  float* p = WP + (size_t)l * 16384;
  int t = threadIdx.x;
  for (int i = t; i < 2048; i += 256) {       // W1 chunks
    int g = i >> 7, r = i & 127;
    int lane = r >> 1, hh = r & 1;
    int off = w1_off(g, lane, hh);
    #pragma unroll
    for (int e = 0; e < 4; e++) {
      int j = hh * 2 + (e >> 1), c = e & 1;
      p[off + e] = w1[(4 * g + j) * H2 + lane * 2 + c];
    }
  }
  for (int i = t; i < 2048; i += 256) {       // W2 chunks
    int g = i >> 6, lane = i & 63;
    int off = 8192 + i * 4;
    #pragma unroll
    for (int j = 0; j < 4; j++)
      p[off + j] = w2[(4 * g + j) * H + lane];
  }
}

// ---------------- encoder: h = x@W+b ; z0 = relu(LN(h; g0,b0)) ----------------
__global__ __launch_bounds__(256) void k_encoder(
    const float* __restrict__ x, const float* __restrict__ Wenc, const float* __restrict__ benc,
    const float* __restrict__ lng, const float* __restrict__ lnb,
    float* __restrict__ h, float* __restrict__ z) {
  __shared__ float Xs[8][IN_CH];
  int t = threadIdx.x;
  int tile = blockIdx.x * 8;
  {
    int r = t >> 5, c4 = t & 31;
    float4 v = ((const float4*)x)[(tile + r) * 32 + c4];
    *(float4*)&Xs[r][c4 * 4] = v;
  }
  __syncthreads();
  int lane = t & 63;
  int wave = __builtin_amdgcn_readfirstlane(t >> 6);
  int n0 = wave * 2;
  float b = benc[lane];
  float a0 = b, a1 = b;
  #pragma unroll
  for (int k = 0; k < IN_CH; k += 4) {
    float4 X0 = *(float4*)&Xs[n0][k];
    float4 X1 = *(float4*)&Xs[n0 + 1][k];
    float w0 = Wenc[(k + 0) * H + lane];
    float w1 = Wenc[(k + 1) * H + lane];
    float w2 = Wenc[(k + 2) * H + lane];
    float w3 = Wenc[(k + 3) * H + lane];
    a0 = fmaf(X0.x, w0, a0); a0 = fmaf(X0.y, w1, a0); a0 = fmaf(X0.z, w2, a0); a0 = fmaf(X0.w, w3, a0);
    a1 = fmaf(X1.x, w0, a1); a1 = fmaf(X1.y, w1, a1); a1 = fmaf(X1.z, w2, a1); a1 = fmaf(X1.w, w3, a1);
  }
  float g = lng[lane], bb = lnb[lane];
  #pragma unroll
  for (int i = 0; i < 2; i++) {
    float a = (i == 0) ? a0 : a1;
    float s = a, q = a * a;
    #pragma unroll
    for (int m = 1; m < 64; m <<= 1) { s += __shfl_xor(s, m); q += __shfl_xor(q, m); }
    float mu = s * (1.0f / 64.0f);
    float var = q * (1.0f / 64.0f) - mu * mu;
    float rs = rsqrtf(var + 1e-5f);
    int gn = tile + n0 + i;
    h[gn * H + lane] = a;
    z[gn * H + lane] = fmaxf(fmaf((a - mu) * rs, g, bb), 0.f);
  }
}

// ---------------- phase A: softmax aggregation (1 node / wave) ----------------
__global__ __launch_bounds__(256) void k_agg(
    const float* __restrict__ zc, const int* __restrict__ offs, const int* __restrict__ csr,
    const float* __restrict__ tvec, float* __restrict__ As, int l) {
  int t = threadIdx.x;
  int lane = t & 63;
  int gn = blockIdx.x * 4 + (t >> 6);
  float tl = tvec[l] * 1.44269504088896340736f;
  int e0 = offs[gn], e1 = offs[gn + 1];
  float d0 = 0.f, d1 = 0.f, d2 = 0.f, d3 = 0.f;
  float a0 = 0.f, a1 = 0.f, a2 = 0.f, a3 = 0.f;
  int e = e0;
  for (; e + 4 <= e1; e += 4) {
    int s0 = csr[e], s1 = csr[e + 1], s2 = csr[e + 2], s3 = csr[e + 3];
    float v0 = zc[s0 * H + lane] + 1e-7f;
    float v1 = zc[s1 * H + lane] + 1e-7f;
    float v2 = zc[s2 * H + lane] + 1e-7f;
    float v3 = zc[s3 * H + lane] + 1e-7f;
    float p0 = exp2f(v0 * tl), p1 = exp2f(v1 * tl);
    float p2 = exp2f(v2 * tl), p3 = exp2f(v3 * tl);
    d0 += p0; d1 += p1; d2 += p2; d3 += p3;
    a0 = fmaf(p0, v0, a0); a1 = fmaf(p1, v1, a1);
    a2 = fmaf(p2, v2, a2); a3 = fmaf(p3, v3, a3);
  }
  for (; e < e1; e++) {
    int s0 = csr[e];
    float v0 = zc[s0 * H + lane] + 1e-7f;
    float p0 = exp2f(v0 * tl);
    d0 += p0; a0 = fmaf(p0, v0, a0);
  }
  float den = (d0 + d1) + (d2 + d3);
  float acc = (a0 + a1) + (a2 + a3);
  As[gn * H + lane] = acc / (den + 1e-16f) + zc[gn * H + lane];
}

// ---------------- phase B/C/D: MLP + residual + next-layer pre-norm ----------------
__global__ __launch_bounds__(256) void k_mlp(
    const float* __restrict__ As_g, float* __restrict__ zn, float* __restrict__ h,
    const float* __restrict__ WP, const float* __restrict__ b1,
    const float* __restrict__ mg, const float* __restrict__ mb,
    const float* __restrict__ b2,
    const float* __restrict__ lngn, const float* __restrict__ lnbn,
    int l, int last) {
  __shared__ float Ws[16384];     // 64 KB: W1 | W2 packed
  __shared__ float Asl[16][H];
  __shared__ float Us[16][H2];
  int t = threadIdx.x;
  int lane = t & 63;
  int wave = __builtin_amdgcn_readfirstlane(t >> 6);
  int tile = blockIdx.x * 16;

  const float* WPl = WP + (size_t)l * 16384;
  #pragma unroll
  for (int i = 0; i < 16; i++) {
    float4 v = *(const float4*)&WPl[(i * 256 + t) * 4];
    *(float4*)&Ws[(i * 256 + t) * 4] = v;
  }
  {
    int r = t >> 4, c = (t & 15) * 4;
    *(float4*)&Asl[r][c] = *(const float4*)&As_g[(tile + r) * H + c];
  }
  __syncthreads();

  int n0 = wave * 4;
  // ---- phase B: u1 = A @ W1 + b1 ; Us = relu(LN(u1))
  {
    const float* b1l = b1 + l * H2;
    int c0 = lane * 2;
    float bb0 = b1l[c0], bb1 = b1l[c0 + 1];
    float u0[4], u1[4];
    #pragma unroll
    for (int i = 0; i < 4; i++) { u0[i] = bb0; u1[i] = bb1; }
    int lb = (lane >> 2) * 8;
    int cA = (2 * (lane & 3) + 0 + (lane >> 2)) & 7;
    int cB = (2 * (lane & 3) + 1 + (lane >> 2)) & 7;
    #pragma unroll
    for (int g = 0; g < 16; g++) {
      float4 wa = *(float4*)&Ws[(g * 128 + lb + cA) * 4];
      float4 wb = *(float4*)&Ws[(g * 128 + lb + cB) * 4];
      #pragma unroll
      for (int i = 0; i < 4; i++) {
        float4 A = *(float4*)&Asl[n0 + i][g * 4];
        u0[i] = fmaf(A.x, wa.x, u0[i]); u1[i] = fmaf(A.x, wa.y, u1[i]);
        u0[i] = fmaf(A.y, wa.z, u0[i]); u1[i] = fmaf(A.y, wa.w, u1[i]);
        u0[i] = fmaf(A.z, wb.x, u0[i]); u1[i] = fmaf(A.z, wb.y, u1[i]);
        u0[i] = fmaf(A.w, wb.z, u0[i]); u1[i] = fmaf(A.w, wb.w, u1[i]);
      }
    }
    float s[4], q[4];
    #pragma unroll
    for (int i = 0; i < 4; i++) { s[i] = u0[i] + u1[i]; q[i] = u0[i] * u0[i] + u1[i] * u1[i]; }
    #pragma unroll
    for (int m = 1; m < 64; m <<= 1) {
      #pragma unroll
      for (int i = 0; i < 4; i++) { s[i] += __shfl_xor(s[i], m); q[i] += __shfl_xor(q[i], m); }
    }
    const float* mgl = mg + l * H2;
    const float* mbl = mb + l * H2;
    float g0 = mgl[c0], g1 = mgl[c0 + 1], hb0 = mbl[c0], hb1 = mbl[c0 + 1];
    #pragma unroll
    for (int i = 0; i < 4; i++) {
      float mu = s[i] * (1.0f / 128.0f);
      float rs = rsqrtf(q[i] * (1.0f / 128.0f) - mu * mu + 1e-5f);
      float o0 = fmaxf(fmaf((u0[i] - mu) * rs, g0, hb0), 0.f);
      float o1 = fmaxf(fmaf((u1[i] - mu) * rs, g1, hb1), 0.f);
      *(float2*)&Us[n0 + i][c0] = make_float2(o0, o1);
    }
  }
  __syncthreads();

  // ---- phase C: u2 = Us @ W2 + b2 ; h += u2 ; phase D: z_next = relu(LN(h))
  {
    const float* b2l = b2 + l * H;
    float bb = b2l[lane];
    float v[4];
    #pragma unroll
    for (int i = 0; i < 4; i++) v[i] = bb;
    #pragma unroll
    for (int g = 0; g < 32; g++) {
      float4 w = *(float4*)&Ws[8192 + (g * 64 + lane) * 4];
      #pragma unroll
      for (int i = 0; i < 4; i++) {
        float4 X = *(float4*)&Us[n0 + i][g * 4];
        v[i] = fmaf(X.x, w.x, v[i]); v[i] = fmaf(X.y, w.y, v[i]);
        v[i] = fmaf(X.z, w.z, v[i]); v[i] = fmaf(X.w, w.w, v[i]);
      }
    }
    float hv[4], s[4], q[4];
    #pragma unroll
    for (int i = 0; i < 4; i++) {
      int gn = tile + n0 + i;
      hv[i] = h[gn * H + lane] + v[i];
      h[gn * H + lane] = hv[i];
      s[i] = hv[i]; q[i] = hv[i] * hv[i];
    }
    if (!last) {
      #pragma unroll
      for (int m = 1; m < 64; m <<= 1) {
        #pragma unroll
        for (int i = 0; i < 4; i++) { s[i] += __shfl_xor(s[i], m); q[i] += __shfl_xor(q[i], m); }
      }
      float gg = lngn[lane], gb = lnbn[lane];
      #pragma unroll
      for (int i = 0; i < 4; i++) {
        float mu = s[i] * (1.0f / 64.0f);
        float rs = rsqrtf(q[i] * (1.0f / 64.0f) - mu * mu + 1e-5f);
        zn[(tile + n0 + i) * H + lane] = fmaxf(fmaf((hv[i] - mu) * rs, gg, gb), 0.f);
      }
    }
  }
}

// ---------------- head: out = h @ Wh + bh ----------------
__global__ __launch_bounds__(256) void k_head(const float* __restrict__ h, const float* __restrict__ Wh,
                                              const float* __restrict__ bh, float* __restrict__ out) {
  __shared__ float Hs[8][H];
  int t = threadIdx.x;
  int tile = blockIdx.x * 8;
  if (t < 128) {
    int r = t >> 4, c4 = t & 15;
    float4 v = ((const float4*)h)[(tile + r) * 16 + c4];
    *(float4*)&Hs[r][c4 * 4] = v;
  }
  __syncthreads();
  int lane = t & 63;
  int wave = __builtin_amdgcn_readfirstlane(t >> 6);
  int n0 = wave * 2;
  int c2 = 64 + ((lane < 48) ? lane : 47);
  float b0 = bh[lane], b1 = bh[c2];
  float a00 = b0, a01 = b1, a10 = b0, a11 = b1;
  #pragma unroll
  for (int k = 0; k < H; k += 4) {
    float4 X0 = *(float4*)&Hs[n0][k];
    float4 X1 = *(float4*)&Hs[n0 + 1][k];
    float wA0 = Wh[(k + 0) * OUT_CH + lane], wB0 = Wh[(k + 0) * OUT_CH + c2];
    float wA1 = Wh[(k + 1) * OUT_CH + lane], wB1 = Wh[(k + 1) * OUT_CH + c2];
    float wA2 = Wh[(k + 2) * OUT_CH + lane], wB2 = Wh[(k + 2) * OUT_CH + c2];
    float wA3 = Wh[(k + 3) * OUT_CH + lane], wB3 = Wh[(k + 3) * OUT_CH + c2];
    a00 = fmaf(X0.x, wA0, a00); a01 = fmaf(X0.x, wB0, a01);
    a00 = fmaf(X0.y, wA1, a00); a01 = fmaf(X0.y, wB1, a01);
    a00 = fmaf(X0.z, wA2, a00); a01 = fmaf(X0.z, wB2, a01);
    a00 = fmaf(X0.w, wA3, a00); a01 = fmaf(X0.w, wB3, a01);
    a10 = fmaf(X1.x, wA0, a10); a11 = fmaf(X1.x, wB0, a11);
    a10 = fmaf(X1.y, wA1, a10); a11 = fmaf(X1.y, wB1, a11);
    a10 = fmaf(X1.z, wA2, a10); a11 = fmaf(X1.z, wB2, a11);
    a10 = fmaf(X1.w, wA3, a10); a11 = fmaf(X1.w, wB3, a11);
  }
  int gn0 = tile + n0;
  out[gn0 * OUT_CH + lane] = a00;
  out[(gn0 + 1) * OUT_CH + lane] = a10;
  if (lane < 48) {
    out[gn0 * OUT_CH + 64 + lane] = a01;
    out[(gn0 + 1) * OUT_CH + 64 + lane] = a11;
  }
}

extern "C" void kernel_launch(void* const* d_in, const int* in_sizes, int n_in,
                              void* d_out, int out_size, void* d_ws, size_t ws_size,
                              hipStream_t stream) {
  (void)in_sizes; (void)n_in; (void)out_size; (void)ws_size;
  const float* x    = (const float*)d_in[0];
  const int*   ei   = (const int*)d_in[1];
  const float* encW = (const float*)d_in[2];
  const float* encb = (const float*)d_in[3];
  const float* lng  = (const float*)d_in[4];
  const float* lnb  = (const float*)d_in[5];
  const float* tv   = (const float*)d_in[6];
  const float* W1   = (const float*)d_in[7];
  const float* b1   = (const float*)d_in[8];
  const float* mg   = (const float*)d_in[9];
  const float* mb   = (const float*)d_in[10];
  const float* W2   = (const float*)d_in[11];
  const float* b2   = (const float*)d_in[12];
  const float* Wh   = (const float*)d_in[13];
  const float* bh   = (const float*)d_in[14];

  char* ws = (char*)d_ws;
  int*   deg  = (int*)(ws + 0);            // N ints
  int*   cur  = (int*)(ws + 40000);        // N ints
  int*   offs = (int*)(ws + 80000);        // N+1 ints
  int*   csr  = (int*)(ws + 120064);       // E ints
  float* h    = (float*)(ws + 760064);     // N*64
  float* z0   = (float*)(ws + 3320064);    // N*64
  float* z1   = (float*)(ws + 5880064);    // N*64
  float* As   = (float*)(ws + 8440064);    // N*64
  float* WP   = (float*)(ws + 11000064);   // 28*16384  (end 12,835,072)

  hipMemsetAsync(ws, 0, 80000, stream);    // deg + cur
  k_count<<<625, 256, 0, stream>>>(ei, deg);
  k_pack<<<28, 256, 0, stream>>>(W1, W2, WP);
  k_scan<<<1, 1024, 0, stream>>>(deg, offs);
  k_fill<<<625, 256, 0, stream>>>(ei, offs, cur, csr);
  k_encoder<<<1250, 256, 0, stream>>>(x, encW, encb, lng, lnb, h, z0);

  float* zc = z0;
  float* znx = z1;
  for (int l = 0; l < NLAYERS; l++) {
    int ln_next = (l + 1 < NLAYERS) ? (l + 1) : l;
    k_agg<<<2500, 256, 0, stream>>>(zc, offs, csr, tv, As, l);
    k_mlp<<<625, 256, 0, stream>>>(As, znx, h, WP, b1, mg, mb, b2,
                                   lng + ln_next * H, lnb + ln_next * H,
                                   l, (l == NLAYERS - 1) ? 1 : 0);
    float* tmp = zc; zc = znx; znx = tmp;
  }
  k_head<<<1250, 256, 0, stream>>>(h, Wh, bh, (float*)d_out);
}